// Round 8
// baseline (156.153 us; speedup 1.0000x reference)
//
#include <hip/hip_runtime.h>

#define NN 8192
#define DD 128
#define CH 16           // column chunks
#define CPC (NN / CH)   // cols per chunk = 512
#define TILES (CPC / 64)

typedef __bf16 bf16x8 __attribute__((ext_vector_type(8)));
typedef float f32x4 __attribute__((ext_vector_type(4)));

#define PACK_INIT __uint_as_float(0x7F7FFFFFu)

// Pack (score, idx): keep high 19 bits of the fp32 score, idx in low 13.
// Monotone bucket-quantization (quantum <= 0.125 for |s|<512); within a
// bucket, smaller idx = smaller float => min-network prefers smaller idx,
// matching reference top_k tie-breaking. Negative scores only occur for
// self (rank-1 by a huge margin), so the inverted idx order there is moot.
static __device__ __forceinline__ float packsi(float s, unsigned idx) {
  return __uint_as_float((__float_as_uint(s) & 0xFFFFE000u) | idx);
}

// Branchless sorted-5 insert (keep 5 smallest): 9 min/max ops, no divergence.
static __device__ __forceinline__ void net5(float& s0, float& s1, float& s2,
                                            float& s3, float& s4, float v) {
  float t1 = fmaxf(s0, v);  s0 = fminf(s0, v);
  float t2 = fmaxf(s1, t1); s1 = fminf(s1, t1);
  float t3 = fmaxf(s2, t2); s2 = fminf(s2, t2);
  float t4 = fmaxf(s3, t3); s3 = fminf(s3, t3);
  s4 = fminf(s4, t4);
}

static __device__ __forceinline__ unsigned short f2bf(float f) {
  unsigned u = __float_as_uint(f);
  u += 0x7FFFu + ((u >> 16) & 1u);   // round-to-nearest-even
  return (unsigned short)(u >> 16);
}

// Kernel 1: f32->bf16 convert, fp32 row sq-norms, zero output scalar.
__global__ __launch_bounds__(256) void prep_kernel(const float* __restrict__ x,
                                                   unsigned short* __restrict__ xb,
                                                   float* __restrict__ sq,
                                                   float* __restrict__ out) {
  const int wave = threadIdx.x >> 6, lane = threadIdx.x & 63;
  const int row = blockIdx.x * 4 + wave;
  const float2 v = ((const float2*)(x + (size_t)row * DD))[lane];
  float ss = v.x * v.x + v.y * v.y;
#pragma unroll
  for (int off = 32; off; off >>= 1) ss += __shfl_down(ss, off);
  if (lane == 0) sq[row] = ss;
  unsigned packed = (unsigned)f2bf(v.x) | ((unsigned)f2bf(v.y) << 16);
  ((unsigned*)(xb + (size_t)row * DD))[lane] = packed;
  if (blockIdx.x == 0 && threadIdx.x == 0) out[0] = 0.0f;
}

// Kernel 2: bf16-MFMA scores + branchless packed top-5 — NO LDS, NO barriers.
// Round-7 lesson: the LDS-staged version is pipe-phase-locked by its per-tile
// __syncthreads (LDS 15us + VALU 22us SUM to the 41us measured). xb (2 MB)
// is L2-resident per XCD, so B fragments are loaded straight from global
// (L2-hit) and the VMEM pipe overlaps the selection VALU instead of summing.
// R=32 rows/wave (two 16-row groups share each B fragment). Block = 128 rows
// x 512 cols; grid (64,16) = 1024 blocks = 4/CU.
__global__ __launch_bounds__(256, 4) void dist_topk_kernel(
    const unsigned short* __restrict__ xb, const float* __restrict__ sq,
    float* __restrict__ pscore) {
  const int t = threadIdx.x;
  const int wave = t >> 6, lane = t & 63;
  const int lrow = lane & 15, lquad = lane >> 4;
  const int rowBase = blockIdx.x * 128;
  const int chunk = blockIdx.y;
  const int j0 = chunk * CPC;

  // My-row fragments (MFMA 2nd operand): lane holds X[row][k=lquad*8+j].
  const int myrow0 = rowBase + wave * 32 + lrow;
  const int myrow1 = myrow0 + 16;
  const unsigned short* ap0 = xb + (size_t)myrow0 * DD + lquad * 8;
  const unsigned short* ap1 = xb + (size_t)myrow1 * DD + lquad * 8;
  bf16x8 a00 = *(const bf16x8*)(ap0);
  bf16x8 a01 = *(const bf16x8*)(ap0 + 32);
  bf16x8 a02 = *(const bf16x8*)(ap0 + 64);
  bf16x8 a03 = *(const bf16x8*)(ap0 + 96);
  bf16x8 a10 = *(const bf16x8*)(ap1);
  bf16x8 a11 = *(const bf16x8*)(ap1 + 32);
  bf16x8 a12 = *(const bf16x8*)(ap1 + 64);
  bf16x8 a13 = *(const bf16x8*)(ap1 + 96);

  // Packed sorted-5 lists, one per row group, named scalars.
  float p00 = PACK_INIT, p01 = PACK_INIT, p02 = PACK_INIT, p03 = PACK_INIT,
        p04 = PACK_INIT;
  float p10 = PACK_INIT, p11 = PACK_INIT, p12 = PACK_INIT, p13 = PACK_INIT,
        p14 = PACK_INIT;

  // Candidate fragment base for this lane: row (j + lrow), k = lquad*8.
  const unsigned short* bbase = xb + (size_t)(j0 + lrow) * DD + lquad * 8;
  const float* sqbase = sq + j0 + lquad * 4;

  for (int it = 0; it < TILES; ++it) {
    const int jt = it * 64;
#pragma unroll
    for (int ct = 0; ct < 4; ++ct) {
      const unsigned short* bp = bbase + (size_t)(jt + ct * 16) * DD;
      bf16x8 b0 = *(const bf16x8*)(bp);
      bf16x8 b1 = *(const bf16x8*)(bp + 32);
      bf16x8 b2 = *(const bf16x8*)(bp + 64);
      bf16x8 b3 = *(const bf16x8*)(bp + 96);
      const f32x4 sq4 = *(const f32x4*)(sqbase + jt + ct * 16);
      f32x4 acc0 = {0.f, 0.f, 0.f, 0.f};
      f32x4 acc1 = {0.f, 0.f, 0.f, 0.f};
      acc0 = __builtin_amdgcn_mfma_f32_16x16x32_bf16(b0, a00, acc0, 0, 0, 0);
      acc1 = __builtin_amdgcn_mfma_f32_16x16x32_bf16(b0, a10, acc1, 0, 0, 0);
      acc0 = __builtin_amdgcn_mfma_f32_16x16x32_bf16(b1, a01, acc0, 0, 0, 0);
      acc1 = __builtin_amdgcn_mfma_f32_16x16x32_bf16(b1, a11, acc1, 0, 0, 0);
      acc0 = __builtin_amdgcn_mfma_f32_16x16x32_bf16(b2, a02, acc0, 0, 0, 0);
      acc1 = __builtin_amdgcn_mfma_f32_16x16x32_bf16(b2, a12, acc1, 0, 0, 0);
      acc0 = __builtin_amdgcn_mfma_f32_16x16x32_bf16(b3, a03, acc0, 0, 0, 0);
      acc1 = __builtin_amdgcn_mfma_f32_16x16x32_bf16(b3, a13, acc1, 0, 0, 0);
      // D = Sc^T: reg r -> cand j0+jt+ct*16+lquad*4+r; lane -> myrow.
      const unsigned colb = (unsigned)(j0 + jt + ct * 16 + lquad * 4);
#pragma unroll
      for (int r = 0; r < 4; ++r) {
        net5(p00, p01, p02, p03, p04, packsi(fmaf(-2.0f, acc0[r], sq4[r]), colb + r));
        net5(p10, p11, p12, p13, p14, packsi(fmaf(-2.0f, acc1[r], sq4[r]), colb + r));
      }
    }
  }

  // Merge across lquads (lanes sharing lrow hold the same two rows).
#pragma unroll
  for (int m = 16; m < 64; m <<= 1) {
    float o0 = __shfl_xor(p00, m), o1 = __shfl_xor(p01, m), o2 = __shfl_xor(p02, m),
          o3 = __shfl_xor(p03, m), o4 = __shfl_xor(p04, m);
    net5(p00, p01, p02, p03, p04, o0);
    net5(p00, p01, p02, p03, p04, o1);
    net5(p00, p01, p02, p03, p04, o2);
    net5(p00, p01, p02, p03, p04, o3);
    net5(p00, p01, p02, p03, p04, o4);
    o0 = __shfl_xor(p10, m); o1 = __shfl_xor(p11, m); o2 = __shfl_xor(p12, m);
    o3 = __shfl_xor(p13, m); o4 = __shfl_xor(p14, m);
    net5(p10, p11, p12, p13, p14, o0);
    net5(p10, p11, p12, p13, p14, o1);
    net5(p10, p11, p12, p13, p14, o2);
    net5(p10, p11, p12, p13, p14, o3);
    net5(p10, p11, p12, p13, p14, o4);
  }
  if (lquad == 0) {
    const size_t b0i = ((size_t)chunk * NN + myrow0) * 5;
    pscore[b0i + 0] = p00; pscore[b0i + 1] = p01; pscore[b0i + 2] = p02;
    pscore[b0i + 3] = p03; pscore[b0i + 4] = p04;
    const size_t b1i = ((size_t)chunk * NN + myrow1) * 5;
    pscore[b1i + 0] = p10; pscore[b1i + 1] = p11; pscore[b1i + 2] = p12;
    pscore[b1i + 3] = p13; pscore[b1i + 4] = p14;
  }
}

// Kernel 3: chunk merge (packed) -> neg idx -> exact fp32 hinge -> atomic mean.
__global__ __launch_bounds__(256) void final_kernel(const float* __restrict__ x,
                                                    const float* __restrict__ pos,
                                                    const float* __restrict__ pscore,
                                                    float* __restrict__ out) {
  const int wave = threadIdx.x >> 6, lane = threadIdx.x & 63;
  const int row = blockIdx.x * 4 + wave;

  float q0 = PACK_INIT, q1 = PACK_INIT, q2 = PACK_INIT, q3 = PACK_INIT,
        q4 = PACK_INIT;
  if (lane < CH) {
    const float* b = pscore + ((size_t)lane * NN + row) * 5;
    q0 = b[0]; q1 = b[1]; q2 = b[2]; q3 = b[3]; q4 = b[4];
  }
#pragma unroll
  for (int m = 1; m < CH; m <<= 1) {
    float o0 = __shfl_xor(q0, m), o1 = __shfl_xor(q1, m), o2 = __shfl_xor(q2, m),
          o3 = __shfl_xor(q3, m), o4 = __shfl_xor(q4, m);
    net5(q0, q1, q2, q3, q4, o0);
    net5(q0, q1, q2, q3, q4, o1);
    net5(q0, q1, q2, q3, q4, o2);
    net5(q0, q1, q2, q3, q4, o3);
    net5(q0, q1, q2, q3, q4, o4);
  }
  const int nidx = (int)(__float_as_uint(__shfl(q4, 0)) & 0x1FFFu);

  const float2 xv  = ((const float2*)(x   + (size_t)row  * DD))[lane];
  const float2 pv  = ((const float2*)(pos + (size_t)row  * DD))[lane];
  const float2 nvv = ((const float2*)(x   + (size_t)nidx * DD))[lane];
  float a0 = xv.x - pv.x + 1e-6f, a1 = xv.y - pv.y + 1e-6f;
  float b0 = xv.x - nvv.x + 1e-6f, b1 = xv.y - nvv.y + 1e-6f;
  float dap = a0 * a0 + a1 * a1;
  float dan = b0 * b0 + b1 * b1;
#pragma unroll
  for (int off = 32; off; off >>= 1) {
    dap += __shfl_down(dap, off);
    dan += __shfl_down(dan, off);
  }
  __shared__ float hs[4];
  if (lane == 0) hs[wave] = fmaxf(sqrtf(dap) - sqrtf(dan) + 0.3f, 0.0f);
  __syncthreads();
  if (threadIdx.x == 0) {
    float s = hs[0] + hs[1] + hs[2] + hs[3];
    atomicAdd(out, s * (1.0f / 8192.0f));
  }
}

extern "C" void kernel_launch(void* const* d_in, const int* in_sizes, int n_in,
                              void* d_out, int out_size, void* d_ws, size_t ws_size,
                              hipStream_t stream) {
  const float* x   = (const float*)d_in[0];
  const float* pos = (const float*)d_in[1];
  float* out = (float*)d_out;

  char* w = (char*)d_ws;
  unsigned short* xb = (unsigned short*)w;                       // 2 MB
  float* sq = (float*)(w + (size_t)NN * DD * 2);                 // 32 KB
  float* pscore = (float*)(w + (size_t)NN * DD * 2 + (size_t)NN * 4);  // 2.62 MB

  prep_kernel<<<NN / 4, 256, 0, stream>>>(x, xb, sq, out);
  dist_topk_kernel<<<dim3(NN / 128, CH), 256, 0, stream>>>(xb, sq, pscore);
  final_kernel<<<NN / 4, 256, 0, stream>>>(x, pos, pscore, out);
}